// Round 15
// baseline (26.466 us; speedup 1.0000x reference)
//
#include <hip/hip_runtime.h>
#include <hip/hip_fp16.h>

#define MROWS 512
#define NCOLS 8192
#define NVALS 4096
#define NB    8192
#define BLOCK 512
#define NW 8
#define EPSF 1e-10f

typedef unsigned int u32;
typedef unsigned long long u64;
typedef unsigned short u16;

#define TOTMASK ((1ull << 44) - 1ull)
#define FXS 1048576.0f          // 2^20 fixed-point scale (exps <= 1 with mx)

// transposed layouts (conflict-free 8- or 16-per-thread chunks)
__device__ __forceinline__ int TP(int e)  { return ((e & 7)  << 9) | (e >> 3); }  // 4096
__device__ __forceinline__ int TPB(int e) { return ((e & 15) << 9) | (e >> 4); }  // 8192
__device__ __forceinline__ u16 f2h(float x) { return __half_as_ushort(__float2half_rn(x)); }
__device__ __forceinline__ float h2f(u16 h) { return __half2float(__ushort_as_half(h)); }

__global__ __launch_bounds__(BLOCK, 2) void listmle_row_kernel(
    const float* __restrict__ outputs,
    const float* __restrict__ runtime,
    const int*   __restrict__ idxs,
    float* __restrict__ row_out)
{
    // 32 (B) + 32 (D) KB + scratch = 64.3 KB -> 2 blocks/CU (grid caps at 2 anyway)
    __shared__ u64 B[NVALS];   // dedup-min (j13|rt24|pred16) -> entries (rt24|j13|exph16) @ TP(pos)
    __shared__ u32 D[NB];      // per-bucket (cnt<<24 | tot*2^20) -> (base<<16 | fp16(S_excl)) (TPB)
    __shared__ u64 s_sc[NW];
    __shared__ float s_ps[NW], s_max[NW];
    __shared__ double s_lg[NW];

    const int tid = threadIdx.x, lane = tid & 63, wave = tid >> 6;
    const int row = blockIdx.x;
    const float* rp = outputs + (size_t)row * NCOLS;
    const float* rr = runtime + (size_t)row * NCOLS;
    const int*   ri = idxs    + (size_t)row * NCOLS;

    // ---- P0: load 16 items/thread; pack pk = (j<<40)|(rt24<<16)|pred_f16; lmax; init ----
    u64 pk[16]; u32 pidx[8];
    float lmax = -INFINITY;
    #pragma unroll
    for (int q = 0; q < 4; ++q) {
        const int b0 = (q << 11) + (tid << 2);
        const int4   i4 = *reinterpret_cast<const int4*>(ri + b0);
        const float4 r4 = *reinterpret_cast<const float4*>(rr + b0);
        const float4 p4 = *reinterpret_cast<const float4*>(rp + b0);
        pidx[q*2]   = ((u32)i4.x & 0xFFFFu) | ((u32)i4.y << 16);
        pidx[q*2+1] = ((u32)i4.z & 0xFFFFu) | ((u32)i4.w << 16);
        const float rv[4] = { r4.x, r4.y, r4.z, r4.w };
        const float pv[4] = { p4.x, p4.y, p4.z, p4.w };
        #pragma unroll
        for (int r = 0; r < 4; ++r) {
            u32 u = (u32)(rv[r] * 16777216.0f);          // exact monotone 24-bit key
            u = u > 0xFFFFFFu ? 0xFFFFFFu : u;
            const u32 j = (u32)b0 + (u32)r;
            pk[q*4+r] = ((u64)j << 40) | ((u64)u << 16) | (u64)f2h(pv[r]);
            lmax = fmaxf(lmax, pv[r]);
        }
    }
    #pragma unroll
    for (int off = 32; off > 0; off >>= 1) lmax = fmaxf(lmax, __shfl_down(lmax, off));
    if (lane == 0) s_max[wave] = lmax;
    #pragma unroll
    for (int i = 0; i < 8; ++i) B[(i<<9)+tid] = ~0ull;
    #pragma unroll
    for (int i = 0; i < 16; ++i) D[(i<<9)+tid] = 0u;
    __syncthreads();                                    // B1

    // ---- P1: dedup + payload in ONE pass: min over j carries (rt24, pred16) ----
    #pragma unroll
    for (int m = 0; m < 16; ++m) {
        const u32 v = (pidx[m>>1] >> ((m & 1) << 4)) & 0xFFFFu;
        atomicMin(&B[TP((int)v)], pk[m]);
    }
    __syncthreads();                                    // B2

    float mx = s_max[0];
    #pragma unroll
    for (int w = 1; w < NW; ++w) mx = fmaxf(mx, s_max[w]);

    // ---- P2: value-owner extracts 8 winners (cf b64); psum; packed u32 count+total
    //          per bucket (integer atomics: exact + commutative -> deterministic) ----
    u64 own[8]; float e8[8];
    u32 keptmask = 0;
    float psum = 0.f;
    #pragma unroll
    for (int i = 0; i < 8; ++i) {
        const u64 x = B[(i<<9)+tid];                    // = B[TP(8*tid+i)]
        own[i] = x;
        if (x != ~0ull) {
            keptmask |= 1u << i;
            const float pd = h2f((u16)(x & 0xFFFFu));
            psum += pd;
            const float e = __expf(pd - mx);            // e <= ~1
            e8[i] = e;
            const int b = (int)((x >> 27) & 0x1FFFu);   // rt24 >> 11
            atomicAdd(&D[TPB(b)], (1u << 24) | (u32)(e * FXS + 0.5f));
        }
    }
    #pragma unroll
    for (int off = 32; off > 0; off >>= 1) psum += __shfl_down(psum, off);
    if (lane == 0) s_ps[wave] = psum;
    __syncthreads();                                    // B2.5: ALL bucket atomicAdds visible
                                                        // (r11/r13/r14 raced here -> absmax 256/640)

    // widened u64 scan of 8192 packed u32 (16/thread, TPB layout)
    u64 d16[16], lsum = 0ull;
    #pragma unroll
    for (int i = 0; i < 16; ++i) {
        const u32 d = D[(i<<9)+tid];
        d16[i] = ((u64)(d >> 24) << 44) | (u64)(d & 0xFFFFFFu);
        lsum += d16[i];
    }
    u64 xsu = lsum;
    #pragma unroll
    for (int off = 1; off < 64; off <<= 1) { const u64 y = __shfl_up(xsu, off); if (lane >= off) xsu += y; }
    if (lane == 63) s_sc[wave] = xsu;
    __syncthreads();                                    // B3 (all D reads complete)

    u64 runp = xsu - lsum, grand = 0ull;
    #pragma unroll
    for (int w = 0; w < NW; ++w) { const u64 t = s_sc[w]; if (w < wave) runp += t; grand += t; }
    const u32 K = (u32)(grand >> 44);
    #pragma unroll
    for (int i = 0; i < 16; ++i) {
        const u32 base = (u32)(runp >> 44);
        const float S = (float)(runp & TOTMASK) * (1.0f / FXS);
        D[(i<<9)+tid] = (base << 16) | (u32)f2h(S);     // fp16 S: rel err 2^-12, range fits
        runp += d16[i];
    }
    __syncthreads();                                    // B4 (packed base|S live)

    // ---- P3: scatter entries (rt24|j13|exph16) by atomic arrival on packed cursor ----
    #pragma unroll
    for (int i = 0; i < 8; ++i) {
        if (keptmask & (1u << i)) {
            const u64 x = own[i];
            const u32 rt24 = (u32)((x >> 16) & 0xFFFFFFu);
            const u32 j    = (u32)((x >> 40) & 0x1FFFu);
            const u32 pos  = atomicAdd(&D[TPB((int)(rt24 >> 11))], 1u << 16) >> 16;
            B[TP((int)pos)] = ((u64)rt24 << 29) | ((u64)j << 16) | (u64)f2h(e8[i]);
        }
    }
    __syncthreads();                                    // B5 (entries in B; D[b]>>16 = end of b)

    // ---- P4: per-entry within-bucket inclusive prefix + log ----
    double logacc = 0.0;
    #pragma unroll
    for (int i = 0; i < 8; ++i) {
        const u32 p = (u32)(8 * tid + i);
        if (p < K) {
            const u64 x = B[(i<<9)+tid];                // = B[TP(p)]
            const u64 ku = x >> 16;                     // 37-bit unique key (rt24|j13)
            const int b  = (int)(x >> 40);              // 13-bit bucket
            const u32 dcur = D[TPB(b)];
            const u32 start = b ? (D[TPB(b - 1)] >> 16) : 0u;
            const u32 end   = dcur >> 16;
            const float S   = h2f((u16)(dcur & 0xFFFFu));
            double dsm = 0.0;
            for (u32 q = start; q < end; ++q) {
                const u64 y = B[TP((int)q)];
                if ((y >> 16) <= ku) dsm += (double)h2f((u16)(y & 0xFFFFu));
            }
            logacc += (double)__logf(S + (float)dsm + EPSF);
        }
    }
    #pragma unroll
    for (int off = 32; off > 0; off >>= 1) logacc += __shfl_down(logacc, off);
    if (lane == 0) s_lg[wave] = logacc;
    __syncthreads();                                    // B6

    if (tid == 0) {
        double lt = 0.0; float pt = 0.f;
        #pragma unroll
        for (int w = 0; w < NW; ++w) { lt += s_lg[w]; pt += s_ps[w]; }
        row_out[row] = (float)(lt - (double)pt + (double)K * (double)mx);
    }
}

__global__ __launch_bounds__(64) void listmle_finalize(
    const float* __restrict__ row_out, float* __restrict__ out)
{
    const int lane = threadIdx.x;
    double acc = 0.0;
    #pragma unroll
    for (int i = 0; i < 8; ++i) acc += (double)row_out[lane + (i << 6)];
    #pragma unroll
    for (int off = 32; off > 0; off >>= 1) acc += __shfl_down(acc, off);
    if (lane == 0) out[0] = (float)(acc / (double)MROWS);
}

extern "C" void kernel_launch(void* const* d_in, const int* in_sizes, int n_in,
                              void* d_out, int out_size, void* d_ws, size_t ws_size,
                              hipStream_t stream) {
    const float* outputs = (const float*)d_in[0];
    const float* runtime = (const float*)d_in[1];
    const int*   idxs    = (const int*)d_in[2];
    float* out = (float*)d_out;
    float* ws  = (float*)d_ws;

    listmle_row_kernel<<<MROWS, BLOCK, 0, stream>>>(outputs, runtime, idxs, ws);
    listmle_finalize<<<1, 64, 0, stream>>>(ws, out);
}

// Round 16
// 26.217 us; speedup vs baseline: 1.0095x; 1.0095x over previous
//
#include <hip/hip_runtime.h>
#include <hip/hip_fp16.h>

#define MROWS 512
#define NCOLS 8192
#define NVALS 4096
#define NB    8192
#define BLOCK 512
#define NW 8
#define EPSF 1e-10f

typedef unsigned int u32;
typedef unsigned long long u64;
typedef unsigned short u16;

#define TOTMASK ((1ull << 44) - 1ull)
#define FXS 1048576.0f          // 2^20 fixed-point scale (exps <= 1 with mx)

// transposed layouts (conflict-free 8- or 16-per-thread chunks)
__device__ __forceinline__ int TP(int e)  { return ((e & 7)  << 9) | (e >> 3); }  // 4096
__device__ __forceinline__ int TPB(int e) { return ((e & 15) << 9) | (e >> 4); }  // 8192
__device__ __forceinline__ u16 f2h(float x) { return __half_as_ushort(__float2half_rn(x)); }
__device__ __forceinline__ float h2f(u16 h) { return __half2float(__ushort_as_half(h)); }

__global__ __launch_bounds__(BLOCK, 2) void listmle_row_kernel(
    const float* __restrict__ outputs,
    const float* __restrict__ runtime,
    const int*   __restrict__ idxs,
    float* __restrict__ row_out)
{
    // 32 (B) + 32 (D) KB + scratch = 64.3 KB -> 2 blocks/CU (grid caps at 2 anyway)
    __shared__ u64 B[NVALS];   // dedup-min (j13|rt24|pred16) -> entries (rt24|j13|exph16) @ TP(pos)
    __shared__ u32 D[NB];      // per-bucket (cnt<<24 | tot*2^20) -> (base<<16 | fp16(S_excl)) (TPB)
    __shared__ u64 s_sc[NW];
    __shared__ float s_ps[NW], s_max[NW];
    __shared__ double s_lg[NW];

    const int tid = threadIdx.x, lane = tid & 63, wave = tid >> 6;
    const int row = blockIdx.x;
    const float* rp = outputs + (size_t)row * NCOLS;
    const float* rr = runtime + (size_t)row * NCOLS;
    const int*   ri = idxs    + (size_t)row * NCOLS;

    // ---- P0a: ISSUE all 12 global loads into registers (issue-early) ----
    int4 i4v[4]; float4 r4v[4], p4v[4];
    #pragma unroll
    for (int q = 0; q < 4; ++q) {
        const int b0 = (q << 11) + (tid << 2);
        i4v[q] = *reinterpret_cast<const int4*>(ri + b0);
        r4v[q] = *reinterpret_cast<const float4*>(rr + b0);
        p4v[q] = *reinterpret_cast<const float4*>(rp + b0);
    }

    // ---- P0b: LDS init (independent of loads -> fills the HBM-latency shadow) ----
    #pragma unroll
    for (int i = 0; i < 8; ++i) B[(i<<9)+tid] = ~0ull;
    #pragma unroll
    for (int i = 0; i < 16; ++i) D[(i<<9)+tid] = 0u;

    // ---- P0c: pack pk = (j<<40)|(rt24<<16)|pred_f16; lmax (consume-late) ----
    u64 pk[16]; u32 pidx[8];
    float lmax = -INFINITY;
    #pragma unroll
    for (int q = 0; q < 4; ++q) {
        const int b0 = (q << 11) + (tid << 2);
        pidx[q*2]   = ((u32)i4v[q].x & 0xFFFFu) | ((u32)i4v[q].y << 16);
        pidx[q*2+1] = ((u32)i4v[q].z & 0xFFFFu) | ((u32)i4v[q].w << 16);
        const float rv[4] = { r4v[q].x, r4v[q].y, r4v[q].z, r4v[q].w };
        const float pv[4] = { p4v[q].x, p4v[q].y, p4v[q].z, p4v[q].w };
        #pragma unroll
        for (int r = 0; r < 4; ++r) {
            u32 u = (u32)(rv[r] * 16777216.0f);          // exact monotone 24-bit key
            u = u > 0xFFFFFFu ? 0xFFFFFFu : u;
            const u32 j = (u32)b0 + (u32)r;
            pk[q*4+r] = ((u64)j << 40) | ((u64)u << 16) | (u64)f2h(pv[r]);
            lmax = fmaxf(lmax, pv[r]);
        }
    }
    #pragma unroll
    for (int off = 32; off > 0; off >>= 1) lmax = fmaxf(lmax, __shfl_down(lmax, off));
    if (lane == 0) s_max[wave] = lmax;
    __syncthreads();                                    // B1

    // ---- P1: dedup + payload in ONE pass: min over j carries (rt24, pred16) ----
    #pragma unroll
    for (int m = 0; m < 16; ++m) {
        const u32 v = (pidx[m>>1] >> ((m & 1) << 4)) & 0xFFFFu;
        atomicMin(&B[TP((int)v)], pk[m]);
    }
    __syncthreads();                                    // B2

    float mx = s_max[0];
    #pragma unroll
    for (int w = 1; w < NW; ++w) mx = fmaxf(mx, s_max[w]);

    // ---- P2: value-owner extracts 8 winners (cf b64); psum; packed u32 count+total
    //          per bucket (integer atomics: exact + commutative -> deterministic) ----
    u64 own[8]; float e8[8];
    u32 keptmask = 0;
    float psum = 0.f;
    #pragma unroll
    for (int i = 0; i < 8; ++i) {
        const u64 x = B[(i<<9)+tid];                    // = B[TP(8*tid+i)]
        own[i] = x;
        if (x != ~0ull) {
            keptmask |= 1u << i;
            const float pd = h2f((u16)(x & 0xFFFFu));
            psum += pd;
            const float e = __expf(pd - mx);            // e <= ~1
            e8[i] = e;
            const int b = (int)((x >> 27) & 0x1FFFu);   // rt24 >> 11
            atomicAdd(&D[TPB(b)], (1u << 24) | (u32)(e * FXS + 0.5f));
        }
    }
    #pragma unroll
    for (int off = 32; off > 0; off >>= 1) psum += __shfl_down(psum, off);
    if (lane == 0) s_ps[wave] = psum;
    __syncthreads();                                    // B2.5: ALL bucket atomicAdds visible

    // widened u64 scan of 8192 packed u32 (16/thread, TPB layout)
    u64 d16[16], lsum = 0ull;
    #pragma unroll
    for (int i = 0; i < 16; ++i) {
        const u32 d = D[(i<<9)+tid];
        d16[i] = ((u64)(d >> 24) << 44) | (u64)(d & 0xFFFFFFu);
        lsum += d16[i];
    }
    u64 xsu = lsum;
    #pragma unroll
    for (int off = 1; off < 64; off <<= 1) { const u64 y = __shfl_up(xsu, off); if (lane >= off) xsu += y; }
    if (lane == 63) s_sc[wave] = xsu;
    __syncthreads();                                    // B3 (all D reads complete)

    u64 runp = xsu - lsum, grand = 0ull;
    #pragma unroll
    for (int w = 0; w < NW; ++w) { const u64 t = s_sc[w]; if (w < wave) runp += t; grand += t; }
    const u32 K = (u32)(grand >> 44);
    #pragma unroll
    for (int i = 0; i < 16; ++i) {
        const u32 base = (u32)(runp >> 44);
        const float S = (float)(runp & TOTMASK) * (1.0f / FXS);
        D[(i<<9)+tid] = (base << 16) | (u32)f2h(S);     // fp16 S: rel err 2^-12, range fits
        runp += d16[i];
    }
    __syncthreads();                                    // B4 (packed base|S live)

    // ---- P3: scatter entries (rt24|j13|exph16) by atomic arrival on packed cursor ----
    #pragma unroll
    for (int i = 0; i < 8; ++i) {
        if (keptmask & (1u << i)) {
            const u64 x = own[i];
            const u32 rt24 = (u32)((x >> 16) & 0xFFFFFFu);
            const u32 j    = (u32)((x >> 40) & 0x1FFFu);
            const u32 pos  = atomicAdd(&D[TPB((int)(rt24 >> 11))], 1u << 16) >> 16;
            B[TP((int)pos)] = ((u64)rt24 << 29) | ((u64)j << 16) | (u64)f2h(e8[i]);
        }
    }
    __syncthreads();                                    // B5 (entries in B; D[b]>>16 = end of b)

    // ---- P4: per-entry within-bucket inclusive prefix + log ----
    double logacc = 0.0;
    #pragma unroll
    for (int i = 0; i < 8; ++i) {
        const u32 p = (u32)(8 * tid + i);
        if (p < K) {
            const u64 x = B[(i<<9)+tid];                // = B[TP(p)]
            const u64 ku = x >> 16;                     // 37-bit unique key (rt24|j13)
            const int b  = (int)(x >> 40);              // 13-bit bucket
            const u32 dcur = D[TPB(b)];
            const u32 start = b ? (D[TPB(b - 1)] >> 16) : 0u;
            const u32 end   = dcur >> 16;
            const float S   = h2f((u16)(dcur & 0xFFFFu));
            double dsm = 0.0;
            for (u32 q = start; q < end; ++q) {
                const u64 y = B[TP((int)q)];
                if ((y >> 16) <= ku) dsm += (double)h2f((u16)(y & 0xFFFFu));
            }
            logacc += (double)__logf(S + (float)dsm + EPSF);
        }
    }
    #pragma unroll
    for (int off = 32; off > 0; off >>= 1) logacc += __shfl_down(logacc, off);
    if (lane == 0) s_lg[wave] = logacc;
    __syncthreads();                                    // B6

    if (tid == 0) {
        double lt = 0.0; float pt = 0.f;
        #pragma unroll
        for (int w = 0; w < NW; ++w) { lt += s_lg[w]; pt += s_ps[w]; }
        row_out[row] = (float)(lt - (double)pt + (double)K * (double)mx);
    }
}

__global__ __launch_bounds__(64) void listmle_finalize(
    const float* __restrict__ row_out, float* __restrict__ out)
{
    const int lane = threadIdx.x;
    double acc = 0.0;
    #pragma unroll
    for (int i = 0; i < 8; ++i) acc += (double)row_out[lane + (i << 6)];
    #pragma unroll
    for (int off = 32; off > 0; off >>= 1) acc += __shfl_down(acc, off);
    if (lane == 0) out[0] = (float)(acc / (double)MROWS);
}

extern "C" void kernel_launch(void* const* d_in, const int* in_sizes, int n_in,
                              void* d_out, int out_size, void* d_ws, size_t ws_size,
                              hipStream_t stream) {
    const float* outputs = (const float*)d_in[0];
    const float* runtime = (const float*)d_in[1];
    const int*   idxs    = (const int*)d_in[2];
    float* out = (float*)d_out;
    float* ws  = (float*)d_ws;

    listmle_row_kernel<<<MROWS, BLOCK, 0, stream>>>(outputs, runtime, idxs, ws);
    listmle_finalize<<<1, 64, 0, stream>>>(ws, out);
}